// Round 3
// baseline (5386.272 us; speedup 1.0000x reference)
//
#include <hip/hip_runtime.h>
#include <hip/hip_bf16.h>

// GCN forward: 2x GCNConv(128->128) + ELU + global mean pool + FC(128->1)
// R2: the compiler serialized R1's 8-deep gather (VGPR=28 proved it).
// Now force 16 gathers in flight per wave via inline-asm global_load_dwordx2
// batches with explicit s_waitcnt + sched_barrier.

#define NODES_PER_BLOCK 4   // waves per block in agg kernels

__global__ void init_kernel(float* __restrict__ deg, int* __restrict__ cnt,
                            float* __restrict__ gsum, int* __restrict__ gcnt, int n) {
    int i = blockIdx.x * blockDim.x + threadIdx.x;
    if (i < n) { deg[i] = 1.0f; cnt[i] = 0; }   // deg starts at 1.0 (self-loop weight)
    if (i < 64) { gsum[i] = 0.0f; gcnt[i] = 0; }
}

__global__ void edge_pass1(const int* __restrict__ dst, const float* __restrict__ ew,
                           float* __restrict__ deg, int* __restrict__ cnt, int E) {
    int e = blockIdx.x * blockDim.x + threadIdx.x;
    if (e >= E) return;
    int d = dst[e];
    atomicAdd(&deg[d], ew[e]);
    atomicAdd(&cnt[d], 1);
}

__global__ void compute_dinv(float* __restrict__ deg, int n) {
    int i = blockIdx.x * blockDim.x + threadIdx.x;
    if (i < n) deg[i] = rsqrtf(deg[i]);   // deg >= 1 always (self-loop)
}

// ---- 3-kernel exclusive scan of cnt -> rowptr ----
__global__ void scan_block(const int* __restrict__ cnt, int* __restrict__ rowptr,
                           int* __restrict__ partial, int n) {
    __shared__ int lds[256];
    int t = threadIdx.x;
    int i = blockIdx.x * 256 + t;
    int v = (i < n) ? cnt[i] : 0;
    lds[t] = v;
    __syncthreads();
    for (int off = 1; off < 256; off <<= 1) {
        int add = (t >= off) ? lds[t - off] : 0;
        __syncthreads();
        lds[t] += add;
        __syncthreads();
    }
    if (i < n) rowptr[i] = lds[t] - v;           // exclusive within block
    if (t == 255) partial[blockIdx.x] = lds[255]; // block total
}

__global__ void scan_partial(int* __restrict__ partial, int nb) {
    __shared__ int lds[1024];
    int t = threadIdx.x;
    int v = (t < nb) ? partial[t] : 0;
    lds[t] = v;
    __syncthreads();
    for (int off = 1; off < 1024; off <<= 1) {
        int add = (t >= off) ? lds[t - off] : 0;
        __syncthreads();
        lds[t] += add;
        __syncthreads();
    }
    if (t < nb) partial[t] = lds[t] - v;          // exclusive
}

__global__ void finalize_rowptr(int* __restrict__ rowptr, const int* __restrict__ partial,
                                int* __restrict__ cursor, int n, int e_total) {
    int i = blockIdx.x * 256 + threadIdx.x;
    if (i < n) {
        int v = rowptr[i] + partial[blockIdx.x];
        rowptr[i] = v;
        cursor[i] = v;
    }
    if (i == 0) rowptr[n] = e_total;
}

__global__ void edge_fill(const int* __restrict__ src, const int* __restrict__ dst,
                          const float* __restrict__ ew, const float* __restrict__ dinv,
                          int* __restrict__ cursor, int2* __restrict__ edges, int E) {
    int e = blockIdx.x * blockDim.x + threadIdx.x;
    if (e >= E) return;
    int s = src[e], d = dst[e];
    float w = dinv[s] * ew[e] * dinv[d];
    int pos = atomicAdd(&cursor[d], 1);
    edges[pos] = make_int2(s, __float_as_int(w));
}

// Y[n][col] = sum_k X[n][k] * W[k][col].  W column held in registers per lane.
__global__ __launch_bounds__(256, 2) void matmul_fc(const float* __restrict__ X,
                                                    const float* __restrict__ W,
                                                    float* __restrict__ Y, int n) {
    int wib = threadIdx.x >> 6, lane = threadIdx.x & 63;
    int wid = blockIdx.x * 4 + wib;
    int half = wid & 1;
    int col = (half << 6) | lane;
    float Wreg[128];
#pragma unroll
    for (int k = 0; k < 128; k++) Wreg[k] = W[k * 128 + col];
    int stride = (gridDim.x * 4) >> 1;
    for (int nn = wid >> 1; nn < n; nn += stride) {
        const float4* xr = (const float4*)(X + (size_t)nn * 128);
        float a0 = 0.f, a1 = 0.f;
#pragma unroll
        for (int k4 = 0; k4 < 32; k4 += 2) {
            float4 xa = xr[k4];
            float4 xb = xr[k4 + 1];
            a0 = fmaf(xa.x, Wreg[4 * k4 + 0], a0);
            a0 = fmaf(xa.y, Wreg[4 * k4 + 1], a0);
            a0 = fmaf(xa.z, Wreg[4 * k4 + 2], a0);
            a0 = fmaf(xa.w, Wreg[4 * k4 + 3], a0);
            a1 = fmaf(xb.x, Wreg[4 * k4 + 4], a1);
            a1 = fmaf(xb.y, Wreg[4 * k4 + 5], a1);
            a1 = fmaf(xb.z, Wreg[4 * k4 + 6], a1);
            a1 = fmaf(xb.w, Wreg[4 * k4 + 7], a1);
        }
        Y[(size_t)nn * 128 + col] = a0 + a1;
    }
}

// 16-deep asm-pinned gather over one node's CSR edge range.
// Each lane owns 2 features (float2 at byte offset lane*8 of a 512B row).
__device__ __forceinline__ float2 gather_row(const float* __restrict__ H,
                                             const int2* __restrict__ edges,
                                             int beg, int end, int lane, float2 init) {
    float2 a0 = init;
    float2 a1 = make_float2(0.f, 0.f);
    float2 a2 = make_float2(0.f, 0.f);
    float2 a3 = make_float2(0.f, 0.f);
    const int lane8 = lane << 3;
    const unsigned long long hb = (unsigned long long)H;
    for (int base = beg; base < end; base += 64) {
        int cnt = end - base; if (cnt > 64) cnt = 64;
        int2 ed = make_int2(0, 0);               // pad: src=0, w=0.0f
        if (lane < cnt) ed = edges[base + lane];
        int es = ed.x;
        float ef = __int_as_float(ed.y);
        int cnt16 = (cnt + 15) & ~15;            // padded lanes gather row 0, w=0
        for (int j = 0; j < cnt16; j += 16) {
#define GRAB(g) int o##g = (__shfl(es, j + g) << 9) | lane8; \
                float w##g = __shfl(ef, j + g);
            GRAB(0) GRAB(1) GRAB(2) GRAB(3) GRAB(4) GRAB(5) GRAB(6) GRAB(7)
            GRAB(8) GRAB(9) GRAB(10) GRAB(11) GRAB(12) GRAB(13) GRAB(14) GRAB(15)
#undef GRAB
            float2 h0, h1, h2, h3, h4, h5, h6, h7;
            float2 h8, h9, h10, h11, h12, h13, h14, h15;
            // 8 loads in flight (no wait)
            asm volatile(
                "global_load_dwordx2 %0, %8,  %16\n\t"
                "global_load_dwordx2 %1, %9,  %16\n\t"
                "global_load_dwordx2 %2, %10, %16\n\t"
                "global_load_dwordx2 %3, %11, %16\n\t"
                "global_load_dwordx2 %4, %12, %16\n\t"
                "global_load_dwordx2 %5, %13, %16\n\t"
                "global_load_dwordx2 %6, %14, %16\n\t"
                "global_load_dwordx2 %7, %15, %16"
                : "=&v"(h0), "=&v"(h1), "=&v"(h2), "=&v"(h3),
                  "=&v"(h4), "=&v"(h5), "=&v"(h6), "=&v"(h7)
                : "v"(o0), "v"(o1), "v"(o2), "v"(o3),
                  "v"(o4), "v"(o5), "v"(o6), "v"(o7), "s"(hb));
            // 8 more; wait for all 16 before any consumer
            asm volatile(
                "global_load_dwordx2 %0, %8,  %16\n\t"
                "global_load_dwordx2 %1, %9,  %16\n\t"
                "global_load_dwordx2 %2, %10, %16\n\t"
                "global_load_dwordx2 %3, %11, %16\n\t"
                "global_load_dwordx2 %4, %12, %16\n\t"
                "global_load_dwordx2 %5, %13, %16\n\t"
                "global_load_dwordx2 %6, %14, %16\n\t"
                "global_load_dwordx2 %7, %15, %16\n\t"
                "s_waitcnt vmcnt(0)"
                : "=&v"(h8), "=&v"(h9), "=&v"(h10), "=&v"(h11),
                  "=&v"(h12), "=&v"(h13), "=&v"(h14), "=&v"(h15)
                : "v"(o8), "v"(o9), "v"(o10), "v"(o11),
                  "v"(o12), "v"(o13), "v"(o14), "v"(o15), "s"(hb)
                : "memory");
            __builtin_amdgcn_sched_barrier(0);   // keep FMAs below the waitcnt
#define ACC(g, ac) ac.x = fmaf(w##g, h##g.x, ac.x); ac.y = fmaf(w##g, h##g.y, ac.y);
            ACC(0, a0) ACC(1, a1) ACC(2, a2) ACC(3, a3)
            ACC(4, a0) ACC(5, a1) ACC(6, a2) ACC(7, a3)
            ACC(8, a0) ACC(9, a1) ACC(10, a2) ACC(11, a3)
            ACC(12, a0) ACC(13, a1) ACC(14, a2) ACC(15, a3)
#undef ACC
        }
    }
    a0.x += a1.x + a2.x + a3.x;
    a0.y += a1.y + a2.y + a3.y;
    return a0;
}

// Aggregation layer 1: out = ELU( dinv[n]^2*H[n] + sum_e w_e*H[src_e] + b1 )
__global__ __launch_bounds__(256, 4) void agg_elu(const float* __restrict__ H,
                                                  const int2* __restrict__ edges,
                                                  const int* __restrict__ rowptr,
                                                  const float* __restrict__ dinv,
                                                  const float* __restrict__ bias,
                                                  float* __restrict__ out, int n) {
    int w = threadIdx.x >> 6, lane = threadIdx.x & 63;
    int node = blockIdx.x * NODES_PER_BLOCK + w;
    if (node >= n) return;
    const float2* Hf2 = (const float2*)H;
    float di = dinv[node];
    float sw = di * di;
    float2 own = Hf2[(size_t)node * 64 + lane];
    float2 acc = gather_row(H, edges, rowptr[node], rowptr[node + 1], lane,
                            make_float2(own.x * sw, own.y * sw));
    float ox = acc.x + bias[2 * lane];
    float oy = acc.y + bias[2 * lane + 1];
    ox = ox > 0.f ? ox : expm1f(ox);
    oy = oy > 0.f ? oy : expm1f(oy);
    ((float2*)out)[(size_t)node * 64 + lane] = make_float2(ox, oy);
}

// Aggregation layer 2 fused with pooling: row = dinv^2*H[n] + sum w*H[s] + b2;
// s_n = row . Wfc ; atomicAdd into per-graph sum + count.
__global__ __launch_bounds__(256, 4) void agg_pool(const float* __restrict__ H,
                                                   const int2* __restrict__ edges,
                                                   const int* __restrict__ rowptr,
                                                   const float* __restrict__ dinv,
                                                   const float* __restrict__ bias,
                                                   const float* __restrict__ wfc,
                                                   const int* __restrict__ batch,
                                                   float* __restrict__ gsum,
                                                   int* __restrict__ gcnt, int n) {
    int w = threadIdx.x >> 6, lane = threadIdx.x & 63;
    int node = blockIdx.x * NODES_PER_BLOCK + w;
    if (node >= n) return;
    const float2* Hf2 = (const float2*)H;
    float di = dinv[node];
    float sw = di * di;
    float2 own = Hf2[(size_t)node * 64 + lane];
    float2 acc = gather_row(H, edges, rowptr[node], rowptr[node + 1], lane,
                            make_float2(own.x * sw, own.y * sw));
    float px = acc.x + bias[2 * lane];
    float py = acc.y + bias[2 * lane + 1];
    float partial = px * wfc[2 * lane] + py * wfc[2 * lane + 1];
#pragma unroll
    for (int off = 32; off; off >>= 1) partial += __shfl_xor(partial, off);
    if (lane == 0) {
        int g = batch[node];
        atomicAdd(&gsum[g], partial);
        atomicAdd(&gcnt[g], 1);
    }
}

__global__ void finalize_out(const float* __restrict__ gsum, const int* __restrict__ gcnt,
                             const float* __restrict__ bfc, float* __restrict__ out) {
    int g = threadIdx.x;
    if (g < 64) {
        float c = (float)gcnt[g];
        out[g] = gsum[g] / fmaxf(c, 1.0f) + bfc[0];
    }
}

extern "C" void kernel_launch(void* const* d_in, const int* in_sizes, int n_in,
                              void* d_out, int out_size, void* d_ws, size_t ws_size,
                              hipStream_t stream) {
    const int N = in_sizes[0] / 128;       // 200000
    const int E = in_sizes[2];             // 6400000

    const float* x     = (const float*)d_in[0];
    const int*   ei    = (const int*)d_in[1];
    const int*   src   = ei;
    const int*   dst   = ei + E;
    const float* ew    = (const float*)d_in[2];
    const int*   batch = (const int*)d_in[3];
    const float* W1    = (const float*)d_in[4];
    const float* b1    = (const float*)d_in[5];
    const float* W2    = (const float*)d_in[6];
    const float* b2    = (const float*)d_in[7];
    const float* Wfc   = (const float*)d_in[8];
    const float* bfc   = (const float*)d_in[9];
    float* out = (float*)d_out;

    // workspace carve (256B aligned)
    char* base = (char*)d_ws;
    size_t off = 0;
    auto carve = [&](size_t bytes) -> void* {
        void* r = base + off;
        off = (off + bytes + 255) & ~(size_t)255;
        return r;
    };
    float* hA      = (float*)carve((size_t)N * 128 * 4);
    float* hB      = (float*)carve((size_t)N * 128 * 4);
    int2*  edges   = (int2*) carve((size_t)E * 8);
    float* deg     = (float*)carve((size_t)N * 4);     // becomes dinv in place
    int*   rowptr  = (int*)  carve((size_t)(N + 1) * 4);
    int*   cursor  = (int*)  carve((size_t)N * 4);     // counts, then fill cursors
    int*   partial = (int*)  carve(1024 * 4);
    float* gsum    = (float*)carve(64 * 4);
    int*   gcnt    = (int*)  carve(64 * 4);

    const int NB = (N + 255) / 256;        // 782 scan blocks (<=1024)
    const int EB = (E + 255) / 256;
    const int AGGB = (N + NODES_PER_BLOCK - 1) / NODES_PER_BLOCK;

    hipLaunchKernelGGL(init_kernel, dim3(NB), dim3(256), 0, stream, deg, cursor, gsum, gcnt, N);
    hipLaunchKernelGGL(edge_pass1, dim3(EB), dim3(256), 0, stream, dst, ew, deg, cursor, E);
    hipLaunchKernelGGL(compute_dinv, dim3(NB), dim3(256), 0, stream, deg, N);
    hipLaunchKernelGGL(scan_block, dim3(NB), dim3(256), 0, stream, cursor, rowptr, partial, N);
    hipLaunchKernelGGL(scan_partial, dim3(1), dim3(1024), 0, stream, partial, NB);
    hipLaunchKernelGGL(finalize_rowptr, dim3(NB), dim3(256), 0, stream, rowptr, partial, cursor, N, E);
    hipLaunchKernelGGL(edge_fill, dim3(EB), dim3(256), 0, stream, src, dst, ew, deg, cursor, edges, E);
    // layer 1
    hipLaunchKernelGGL(matmul_fc, dim3(2048), dim3(256), 0, stream, x, W1, hA, N);
    hipLaunchKernelGGL(agg_elu, dim3(AGGB), dim3(256), 0, stream, hA, edges, rowptr, deg, b1, hB, N);
    // layer 2
    hipLaunchKernelGGL(matmul_fc, dim3(2048), dim3(256), 0, stream, hB, W2, hA, N);
    hipLaunchKernelGGL(agg_pool, dim3(AGGB), dim3(256), 0, stream, hA, edges, rowptr, deg, b2, Wfc, batch, gsum, gcnt, N);
    // pool finalize
    hipLaunchKernelGGL(finalize_out, dim3(1), dim3(64), 0, stream, gsum, gcnt, bfc, out);
}